// Round 8
// baseline (251.100 us; speedup 1.0000x reference)
//
#include <hip/hip_runtime.h>
#include <cmath>

#define NPTS 262144
#define NLVL 16
#define NDENSE 5
#define NHASH 11
#define HASH_MASK 0x7FFFFu

#define PPT 2                                  // points per thread
#define CHUNK (256 * PPT)                      // 512 points per block
#define CHUNKS_PER_LVL (NPTS / CHUNK)          // 512
#define HASH_UNITS (NHASH * CHUNKS_PER_LVL)    // 5632
#define UNITS_PER_XCD (HASH_UNITS / 8)         // 704
#define DENSE_UNITS (NDENSE * CHUNKS_PER_LVL)  // 2560
#define TOTAL_UNITS (HASH_UNITS + DENSE_UNITS) // 8192

typedef float vf2 __attribute__((ext_vector_type(2)));
typedef float vf4 __attribute__((ext_vector_type(4)));

struct Meta {
    float scale[NLVL];
    unsigned off[NLVL];
    unsigned res[NLVL];   // only used for dense levels
};

// ---------------- hash level inner (hsize = 2^19, pow2 mask) ----------------
// Divergent even/odd pairing (round-6 inner, best measured): even ix loads
// one aligned float4 per corner-pair (4 reqs/pt); odd ix does 8 float2s.
// Wave-average ~6 line requests/point.
__device__ __forceinline__ vf2 hash_level(
    const float* __restrict__ emb, unsigned off, float s,
    float x, float y, float z)
{
    const float px = x * s, py = y * s, pz = z * s;
    const float gx = floorf(px), gy = floorf(py), gz = floorf(pz);
    const float fx = px - gx, fy = py - gy, fz = pz - gz;
    const unsigned ix = (unsigned)gx, iy = (unsigned)gy, iz = (unsigned)gz;

    const unsigned hy0 = iy * 2654435761u, hy1 = hy0 + 2654435761u;
    const unsigned hz0 = iz * 805459861u,  hz1 = hz0 + 805459861u;
    const unsigned hyz[4] = {hy0 ^ hz0, hy1 ^ hz0, hy0 ^ hz1, hy1 ^ hz1};

    const float wy0 = 1.0f - fy, wz0 = 1.0f - fz;
    const float wc[4] = {wy0 * wz0, fy * wz0, wy0 * fz, fy * fz};
    const float wx0 = 1.0f - fx;

    const vf2* __restrict__ emb2 = (const vf2*)emb;
    const vf4* __restrict__ emb4 = (const vf4*)emb;

    float a0 = 0.0f, a1 = 0.0f;
    if ((ix & 1u) == 0u) {
#pragma unroll
        for (int c = 0; c < 4; ++c) {
            const unsigned i0 = (ix ^ hyz[c]) & HASH_MASK;
            const vf4 f = emb4[(off + (i0 & ~1u)) >> 1];
            const bool sw = (i0 & 1u);
            const float c0x = sw ? f.z : f.x, c0y = sw ? f.w : f.y;
            const float c1x = sw ? f.x : f.z, c1y = sw ? f.y : f.w;
            a0 += wc[c] * (wx0 * c0x + fx * c1x);
            a1 += wc[c] * (wx0 * c0y + fx * c1y);
        }
    } else {
#pragma unroll
        for (int c = 0; c < 4; ++c) {
            const unsigned i0 = (ix        ^ hyz[c]) & HASH_MASK;
            const unsigned i1 = ((ix + 1u) ^ hyz[c]) & HASH_MASK;
            const vf2 f0 = emb2[off + i0];
            const vf2 f1 = emb2[off + i1];
            a0 += wc[c] * (wx0 * f0.x + fx * f1.x);
            a1 += wc[c] * (wx0 * f0.y + fx * f1.y);
        }
    }
    vf2 r; r.x = a0; r.y = a1;
    return r;
}

__device__ __forceinline__ vf2 dense_level(
    const float* __restrict__ emb, unsigned off, unsigned r, float s,
    float x, float y, float z)
{
    const float px = x * s, py = y * s, pz = z * s;
    const float gx = floorf(px), gy = floorf(py), gz = floorf(pz);
    const float fx = px - gx, fy = py - gy, fz = pz - gz;
    const unsigned ix = (unsigned)gx, iy = (unsigned)gy, iz = (unsigned)gz;

    const unsigned base = ix + iy * r + iz * r * r + off;
    const unsigned dy = r, dz = r * r;

    const vf2* __restrict__ emb2 = (const vf2*)emb;
    vf2 f[8];
    f[0] = emb2[base];           f[1] = emb2[base + 1];
    f[2] = emb2[base + dy];      f[3] = emb2[base + dy + 1];
    f[4] = emb2[base + dz];      f[5] = emb2[base + dz + 1];
    f[6] = emb2[base + dz + dy]; f[7] = emb2[base + dz + dy + 1];

    const float wx0 = 1.0f - fx, wy0 = 1.0f - fy, wz0 = 1.0f - fz;
    const float w00 = wz0 * wy0, w01 = wz0 * fy, w10 = fz * wy0, w11 = fz * fy;
    vf2 a;
    a.x = w00 * (wx0 * f[0].x + fx * f[1].x) + w01 * (wx0 * f[2].x + fx * f[3].x)
        + w10 * (wx0 * f[4].x + fx * f[5].x) + w11 * (wx0 * f[6].x + fx * f[7].x);
    a.y = w00 * (wx0 * f[0].y + fx * f[1].y) + w01 * (wx0 * f[2].y + fx * f[3].y)
        + w10 * (wx0 * f[4].y + fx * f[5].y) + w11 * (wx0 * f[6].y + fx * f[7].y);
    return a;
}

// All 16 levels, level-major ws output.
// Blocks [0, 5632): hash levels 5..15, XCD-affine balanced (round-6 map):
//   g = (b&7)*704 + (b>>3); level = 5 + g/512, chunk = g%512.
// Blocks [5632, 8192): dense levels 0..4 (cheap, fill the scheduling tail):
//   d = b - 5632; level = d/512, chunk = d%512.
__global__ __launch_bounds__(256) void encode(
    const float* __restrict__ means, const float* __restrict__ emb,
    float* __restrict__ ws, Meta meta)
{
    const unsigned b = blockIdx.x;
    unsigned lvl, chk;
    if (b < HASH_UNITS) {
        const unsigned g = (b & 7u) * UNITS_PER_XCD + (b >> 3);
        lvl = NDENSE + (g >> 9);
        chk = g & 511u;
    } else {
        const unsigned d = b - HASH_UNITS;
        lvl = d >> 9;
        chk = d & 511u;
    }

    const float sc     = meta.scale[lvl];
    const unsigned off = meta.off[lvl];
    const unsigned r   = meta.res[lvl];

    const unsigned p0 = chk * CHUNK + threadIdx.x;
    vf2* __restrict__ ws2 = (vf2*)ws;

#pragma unroll
    for (int pp = 0; pp < PPT; ++pp) {
        const unsigned p = p0 + (unsigned)pp * 256u;
        const float x = (means[3 * p + 0] + 1.0f) * 0.5f;
        const float y = (means[3 * p + 1] + 1.0f) * 0.5f;
        const float z = (means[3 * p + 2] + 1.0f) * 0.5f;

        vf2 a;
        if (lvl >= NDENSE) a = hash_level(emb, off, sc, x, y, z);
        else               a = dense_level(emb, off, r, sc, x, y, z);

        // ws is stream-once: bypass L2 to protect table residency
        __builtin_nontemporal_store(a, &ws2[(size_t)lvl * NPTS + p]);
    }
}

// ------- pure transpose: ws[level][point] -> out[point][level], no gathers -------
__global__ __launch_bounds__(256) void transpose_out(
    const float* __restrict__ ws, float* __restrict__ out)
{
    const int p = blockIdx.x * 256 + threadIdx.x;
    const vf2* __restrict__ ws2 = (const vf2*)ws;

    vf2 h[NLVL];
#pragma unroll
    for (int l = 0; l < NLVL; ++l)
        h[l] = ws2[(size_t)l * NPTS + p];

    float* o = out + (size_t)p * (2 * NLVL);
#pragma unroll
    for (int k = 0; k < 8; ++k) {
        vf4 v;
        v.x = h[2 * k].x; v.y = h[2 * k].y; v.z = h[2 * k + 1].x; v.w = h[2 * k + 1].y;
        __builtin_nontemporal_store(v, (vf4*)(o + 4 * k));
    }
}

// ---------- fallbacks (smaller ws) ----------
__global__ __launch_bounds__(256) void enc_hash_direct(
    const float* __restrict__ means, const float* __restrict__ emb,
    float* __restrict__ dst, Meta meta)
{
    const unsigned b   = blockIdx.x;
    const unsigned g   = (b & 7u) * UNITS_PER_XCD + (b >> 3);
    const unsigned lvl = NDENSE + (g >> 9);
    const unsigned chk = g & 511u;
    const float sc     = meta.scale[lvl];
    const unsigned off = meta.off[lvl];
    const unsigned p0  = chk * CHUNK + threadIdx.x;
    vf2* __restrict__ dst2 = (vf2*)dst;
#pragma unroll
    for (int pp = 0; pp < PPT; ++pp) {
        const unsigned p = p0 + (unsigned)pp * 256u;
        const float x = (means[3 * p + 0] + 1.0f) * 0.5f;
        const float y = (means[3 * p + 1] + 1.0f) * 0.5f;
        const float z = (means[3 * p + 2] + 1.0f) * 0.5f;
        dst2[(size_t)p * NLVL + lvl] = hash_level(emb, off, sc, x, y, z);
    }
}

__global__ __launch_bounds__(256) void enc_dense_direct(
    const float* __restrict__ means, const float* __restrict__ emb,
    float* __restrict__ dst, Meta meta)
{
    const int p = blockIdx.x * 256 + threadIdx.x;
    const int l = blockIdx.y;
    const float x = (means[3 * p + 0] + 1.0f) * 0.5f;
    const float y = (means[3 * p + 1] + 1.0f) * 0.5f;
    const float z = (means[3 * p + 2] + 1.0f) * 0.5f;
    ((vf2*)dst)[(size_t)p * NLVL + l] =
        dense_level(emb, meta.off[l], meta.res[l], meta.scale[l], x, y, z);
}

extern "C" void kernel_launch(void* const* d_in, const int* in_sizes, int n_in,
                              void* d_out, int out_size, void* d_ws, size_t ws_size,
                              hipStream_t stream)
{
    const float* means = (const float*)d_in[0];
    const float* emb   = (const float*)d_in[1];
    float* out         = (float*)d_out;

    Meta m;
    const double lg = log2(1.38191288);
    unsigned off = 0;
    for (int l = 0; l < NLVL; ++l) {
        const double scale_d = pow(2.0, (double)l * lg) * 16.0 - 1.0;
        m.scale[l] = (float)scale_d;
        m.res[l]   = (unsigned)ceil(scale_d) + 1u;

        const double gres_d = ceil(16.0 * pow(1.38191288, (double)l));
        unsigned long long r3 = (unsigned long long)gres_d;
        r3 = r3 * r3 * r3;
        unsigned long long pl = r3 < (1ull << 19) ? r3 : (1ull << 19);
        pl = (pl + 7ull) / 8ull * 8ull;

        m.off[l] = off;
        off += (unsigned)pl;
    }

    const size_t ws_full = (size_t)NLVL * NPTS * sizeof(vf2);   // 32 MB
    if (ws_size >= ws_full) {
        float* ws = (float*)d_ws;
        encode<<<TOTAL_UNITS, 256, 0, stream>>>(means, emb, ws, m);
        transpose_out<<<NPTS / 256, 256, 0, stream>>>(ws, out);
    } else {
        enc_hash_direct<<<HASH_UNITS, 256, 0, stream>>>(means, emb, out, m);
        enc_dense_direct<<<dim3(NPTS / 256, NDENSE, 1), 256, 0, stream>>>(means, emb, out, m);
    }
}